// Round 1
// baseline (2395.576 us; speedup 1.0000x reference)
//
#include <hip/hip_runtime.h>
#include <hip/hip_bf16.h>

#define NN 50000
#define EE 800000
#define BB 512
#define HH 96
#define DIN 5
#define DOUT 192
#define EPSV 1e-5f

// ---------------- degree ----------------
__global__ void k_degcount(const int* __restrict__ dst, float* __restrict__ deg) {
    int e = blockIdx.x * blockDim.x + threadIdx.x;
    if (e < EE) atomicAdd(&deg[dst[e]], 1.0f);
}

__global__ void k_dinv(float* __restrict__ deg) {
    int i = blockIdx.x * blockDim.x + threadIdx.x;
    if (i < NN) deg[i] = rsqrtf(deg[i] + 1.0f);
}

// ---------------- input layer: h = relu(x @ W_in + b_in) ----------------
__global__ void k_inlayer(const float* __restrict__ x, const float* __restrict__ Win,
                          const float* __restrict__ bin, float* __restrict__ h) {
    int i = blockIdx.x * blockDim.x + threadIdx.x;
    if (i >= NN * HH) return;
    int n = i / HH, j = i % HH;
    float acc = bin[j];
#pragma unroll
    for (int k = 0; k < DIN; ++k) acc += x[n * DIN + k] * Win[k * HH + j];
    h[i] = fmaxf(acc, 0.0f);
}

// ---------------- 96x96 GEMM: C[n,:] = A[n,:] @ W ----------------
// 64 rows per block, 256 threads: thread = (row r = tid>>2, col-quarter q = tid&3, 24 cols)
__global__ __launch_bounds__(256) void k_gemm96(const float* __restrict__ A,
                                                const float* __restrict__ W,
                                                float* __restrict__ C, int nrows) {
    __shared__ float sA[64][100];   // +4 pad: kills 16-way bank conflict on column reads
    __shared__ float sW[96 * 96];
    int tid = threadIdx.x;
    int row0 = blockIdx.x * 64;

    for (int i = tid; i < 96 * 96; i += 256) sW[i] = W[i];
    for (int i = tid; i < 64 * 96; i += 256) {
        int r = i / 96, c = i % 96;
        int gr = row0 + r;
        sA[r][c] = (gr < nrows) ? A[gr * 96 + c] : 0.0f;
    }
    __syncthreads();

    int r = tid >> 2;
    int j0 = (tid & 3) * 24;
    float acc[24];
#pragma unroll
    for (int jj = 0; jj < 24; ++jj) acc[jj] = 0.0f;

    for (int k = 0; k < 96; ++k) {
        float a = sA[r][k];
#pragma unroll
        for (int jj = 0; jj < 24; ++jj) acc[jj] += a * sW[k * 96 + j0 + jj];
    }

    int gr = row0 + r;
    if (gr < nrows) {
#pragma unroll
        for (int jj = 0; jj < 24; jj += 4) {
            float4 v = make_float4(acc[jj], acc[jj + 1], acc[jj + 2], acc[jj + 3]);
            *reinterpret_cast<float4*>(&C[gr * 96 + j0 + jj]) = v;
        }
    }
}

// ---------------- self-loop init: agg = hw * dinv^2 ----------------
__global__ void k_selfinit(const float* __restrict__ hw, const float* __restrict__ dinv,
                           float* __restrict__ agg) {
    int i = blockIdx.x * blockDim.x + threadIdx.x;
    if (i >= NN * HH) return;
    int n = i / HH;
    float d = dinv[n];
    agg[i] = hw[i] * d * d;
}

// ---------------- edge scatter: agg[dst] += hw[src] * dinv[s]*dinv[d] ----------------
// one thread = one edge x 4 consecutive features (float4 gather, 4 atomics)
__global__ void k_scatter(const float* __restrict__ hw, const float* __restrict__ dinv,
                          const int* __restrict__ src, const int* __restrict__ dst,
                          float* __restrict__ agg) {
    int gid = blockIdx.x * blockDim.x + threadIdx.x;
    if (gid >= EE * 24) return;
    int e = gid / 24;
    int jq = (gid % 24) * 4;
    int s = src[e], d = dst[e];
    float c = dinv[s] * dinv[d];
    float4 hv = *reinterpret_cast<const float4*>(&hw[s * 96 + jq]);
    float* ap = &agg[d * 96 + jq];
    atomicAdd(ap + 0, hv.x * c);
    atomicAdd(ap + 1, hv.y * c);
    atomicAdd(ap + 2, hv.z * c);
    atomicAdd(ap + 3, hv.w * c);
}

// ---------------- per-column sum / sumsq ----------------
__global__ void k_colstats(const float* __restrict__ h, float* __restrict__ stats) {
    __shared__ float ssum[96], ssq[96];
    int tid = threadIdx.x;
    if (tid < 96) { ssum[tid] = 0.0f; ssq[tid] = 0.0f; }
    __syncthreads();
    for (int i = blockIdx.x * blockDim.x + tid; i < NN * HH; i += gridDim.x * blockDim.x) {
        float v = h[i];
        int j = i % 96;
        atomicAdd(&ssum[j], v);
        atomicAdd(&ssq[j], v * v);
    }
    __syncthreads();
    if (tid < 96) {
        atomicAdd(&stats[tid], ssum[tid]);
        atomicAdd(&stats[96 + tid], ssq[tid]);
    }
}

// ---------------- fold mean/var into per-column scale/shift ----------------
__global__ void k_bnprep(float* __restrict__ stats, const float* __restrict__ g,
                         const float* __restrict__ be) {
    int j = threadIdx.x;
    if (j < 96) {
        float m = stats[j] * (1.0f / NN);
        float var = stats[96 + j] * (1.0f / NN) - m * m;
        float sc = g[j] * rsqrtf(var + EPSV);
        stats[j] = sc;
        stats[96 + j] = be[j] - m * sc;
    }
}

// ---------------- h_new = relu(agg*sc + sh) + h_prev ----------------
__global__ void k_bnapply(const float* __restrict__ agg, const float* __restrict__ hprev,
                          const float* __restrict__ stats, float* __restrict__ hnew) {
    int i = blockIdx.x * blockDim.x + threadIdx.x;
    if (i >= NN * HH) return;
    int j = i % 96;
    float v = fmaxf(agg[i] * stats[j] + stats[96 + j], 0.0f);
    hnew[i] = v + hprev[i];
}

// ---------------- segment-sum pooling ----------------
__global__ void k_pool(const float* __restrict__ h, const int* __restrict__ batch,
                       float* __restrict__ pooled, float* __restrict__ counts) {
    int i = blockIdx.x * blockDim.x + threadIdx.x;
    if (i >= NN * HH) return;
    int n = i / 96, j = i % 96;
    int b = batch[n];
    atomicAdd(&pooled[b * 96 + j], h[i]);
    if (j == 0) atomicAdd(&counts[b], 1.0f);
}

// ---------------- out = LN(pooled/cnt @ W_out + b_out) ----------------
__global__ __launch_bounds__(192) void k_out(const float* __restrict__ pooled,
                                             const float* __restrict__ counts,
                                             const float* __restrict__ Wout,
                                             const float* __restrict__ bout,
                                             const float* __restrict__ lg,
                                             const float* __restrict__ lb,
                                             float* __restrict__ out) {
    __shared__ float sp[96];
    __shared__ float smv[2];
    int b = blockIdx.x, t = threadIdx.x;
    float inv = 1.0f / fmaxf(counts[b], 1.0f);
    if (t < 96) sp[t] = pooled[b * 96 + t] * inv;
    __syncthreads();

    float acc = bout[t];
    for (int k = 0; k < 96; ++k) acc += sp[k] * Wout[k * 192 + t];

    __shared__ float svals[192];
    svals[t] = acc;
    __syncthreads();
    if (t < 64) {
        float a0 = svals[t], a1 = svals[t + 64], a2 = svals[t + 128];
        float s = a0 + a1 + a2;
        float s2 = a0 * a0 + a1 * a1 + a2 * a2;
        for (int o = 32; o > 0; o >>= 1) {
            s += __shfl_down(s, o, 64);
            s2 += __shfl_down(s2, o, 64);
        }
        if (t == 0) { smv[0] = s * (1.0f / 192.0f); smv[1] = s2 * (1.0f / 192.0f); }
    }
    __syncthreads();
    float m = smv[0];
    float var = smv[1] - m * m;
    float r = rsqrtf(var + EPSV);
    out[b * 192 + t] = lg[t] * (acc - m) * r + lb[t];
}

extern "C" void kernel_launch(void* const* d_in, const int* in_sizes, int n_in,
                              void* d_out, int out_size, void* d_ws, size_t ws_size,
                              hipStream_t stream) {
    const float* x    = (const float*)d_in[0];
    const int*   ei   = (const int*)  d_in[1];
    const int*   batch= (const int*)  d_in[2];
    const float* Win  = (const float*)d_in[3];
    const float* bin  = (const float*)d_in[4];
    const float* W1   = (const float*)d_in[5];
    const float* g1   = (const float*)d_in[7];
    const float* be1  = (const float*)d_in[8];
    const float* W2   = (const float*)d_in[9];
    const float* g2   = (const float*)d_in[11];
    const float* be2  = (const float*)d_in[12];
    const float* Wout = (const float*)d_in[13];
    const float* bout = (const float*)d_in[14];
    const float* lg   = (const float*)d_in[15];
    const float* lb   = (const float*)d_in[16];
    const int* src = ei;
    const int* dst = ei + EE;

    float* ws     = (float*)d_ws;
    float* hA     = ws;                        // [N,H]
    float* hB     = hA + (size_t)NN * HH;      // [N,H]
    float* hC     = hB + (size_t)NN * HH;      // [N,H]
    float* dinv   = hC + (size_t)NN * HH;      // [N]
    float* stats  = dinv + NN;                 // [2H]
    float* pooled = stats + 2 * HH;            // [B,H]
    float* counts = pooled + (size_t)BB * HH;  // [B]

    const int NH = NN * HH;
    const int TB = 256;

    // degrees (shared by both layers)
    hipMemsetAsync(dinv, 0, NN * sizeof(float), stream);
    k_degcount<<<(EE + TB - 1) / TB, TB, 0, stream>>>(dst, dinv);
    k_dinv<<<(NN + TB - 1) / TB, TB, 0, stream>>>(dinv);

    // input layer -> hA
    k_inlayer<<<(NH + TB - 1) / TB, TB, 0, stream>>>(x, Win, bin, hA);

    const float* Ws[2]  = {W1, W2};
    const float* gs[2]  = {g1, g2};
    const float* bes[2] = {be1, be2};
    float* prev[2] = {hA, hB};
    float* hw[2]   = {hB, hC};
    float* agg[2]  = {hC, hA};
    float* hnew[2] = {hB, hC};
    // layer0: prev=hA, hw=hB, agg=hC, hnew->hB (hB's hw is dead by then)
    // layer1: prev=hB, hw=hC, agg=hA, hnew->hC

    for (int l = 0; l < 2; ++l) {
        k_gemm96<<<(NN + 63) / 64, TB, 0, stream>>>(prev[l], Ws[l], hw[l], NN);
        k_selfinit<<<(NH + TB - 1) / TB, TB, 0, stream>>>(hw[l], dinv, agg[l]);
        k_scatter<<<(EE * 24 + TB - 1) / TB, TB, 0, stream>>>(hw[l], dinv, src, dst, agg[l]);
        hipMemsetAsync(stats, 0, 2 * HH * sizeof(float), stream);
        k_colstats<<<1024, TB, 0, stream>>>(agg[l], stats);
        k_bnprep<<<1, 128, 0, stream>>>(stats, gs[l], bes[l]);
        k_bnapply<<<(NH + TB - 1) / TB, TB, 0, stream>>>(agg[l], prev[l], stats, hnew[l]);
    }

    // pooling
    hipMemsetAsync(pooled, 0, (size_t)(BB * HH + BB) * sizeof(float), stream);
    k_pool<<<(NH + TB - 1) / TB, TB, 0, stream>>>(hC, batch, pooled, counts);

    // readout + layernorm
    k_out<<<BB, 192, 0, stream>>>(pooled, counts, Wout, bout, lg, lb, (float*)d_out);
}

// Round 2
// 572.179 us; speedup vs baseline: 4.1868x; 4.1868x over previous
//
#include <hip/hip_runtime.h>
#include <hip/hip_bf16.h>

#define NN 50000
#define EE 800000
#define BB 512
#define HH 96
#define DIN 5
#define DOUT 192
#define EPSV 1e-5f

// ---------------- degree histogram (int) ----------------
__global__ void k_deghist(const int* __restrict__ dst, int* __restrict__ degi) {
    int e = blockIdx.x * blockDim.x + threadIdx.x;
    if (e < EE) atomicAdd(&degi[dst[e]], 1);
}

__global__ void k_dinv(const int* __restrict__ degi, float* __restrict__ dinv) {
    int i = blockIdx.x * blockDim.x + threadIdx.x;
    if (i < NN) dinv[i] = rsqrtf((float)degi[i] + 1.0f);
}

// ---------------- exclusive prefix sum over degi -> row_ptr (single block) ----------------
__global__ __launch_bounds__(1024) void k_scan(const int* __restrict__ degi,
                                               int* __restrict__ row_ptr) {
    __shared__ int wsum[16];
    __shared__ int woff[16];
    __shared__ int carry_s;
    int tid = threadIdx.x;
    int lane = tid & 63, w = tid >> 6;
    if (tid == 0) carry_s = 0;
    __syncthreads();
    for (int base = 0; base < NN; base += 1024) {
        int i = base + tid;
        int v = (i < NN) ? degi[i] : 0;
        int x = v;
#pragma unroll
        for (int o = 1; o < 64; o <<= 1) {
            int y = __shfl_up(x, o, 64);
            if (lane >= o) x += y;
        }
        if (lane == 63) wsum[w] = x;
        __syncthreads();
        if (tid == 0) {
            int c = carry_s;
#pragma unroll
            for (int k = 0; k < 16; ++k) { woff[k] = c; c += wsum[k]; }
            carry_s = c;
        }
        __syncthreads();
        if (i < NN) row_ptr[i] = woff[w] + x - v;
        __syncthreads();   // wsum/woff reused next iteration
    }
    if (tid == 0) row_ptr[NN] = carry_s;
}

// ---------------- CSR fill: group edges by dst, precompute coef ----------------
__global__ void k_fill(const int* __restrict__ src, const int* __restrict__ dst,
                       const float* __restrict__ dinv, int* __restrict__ cursor,
                       int* __restrict__ col, float* __restrict__ coef) {
    int e = blockIdx.x * blockDim.x + threadIdx.x;
    if (e >= EE) return;
    int s = src[e], d = dst[e];
    int p = atomicAdd(&cursor[d], 1);
    col[p] = s;
    coef[p] = dinv[s] * dinv[d];
}

// ---------------- input layer: h = relu(x @ W_in + b_in) ----------------
__global__ void k_inlayer(const float* __restrict__ x, const float* __restrict__ Win,
                          const float* __restrict__ bin, float* __restrict__ h) {
    int i = blockIdx.x * blockDim.x + threadIdx.x;
    if (i >= NN * HH) return;
    int n = i / HH, j = i % HH;
    float acc = bin[j];
#pragma unroll
    for (int k = 0; k < DIN; ++k) acc += x[n * DIN + k] * Win[k * HH + j];
    h[i] = fmaxf(acc, 0.0f);
}

// ---------------- 96x96 GEMM: C[n,:] = A[n,:] @ W ----------------
__global__ __launch_bounds__(256) void k_gemm96(const float* __restrict__ A,
                                                const float* __restrict__ W,
                                                float* __restrict__ C, int nrows) {
    __shared__ float sA[64][100];
    __shared__ float sW[96 * 96];
    int tid = threadIdx.x;
    int row0 = blockIdx.x * 64;

    for (int i = tid; i < 96 * 96; i += 256) sW[i] = W[i];
    for (int i = tid; i < 64 * 96; i += 256) {
        int r = i / 96, c = i % 96;
        int gr = row0 + r;
        sA[r][c] = (gr < nrows) ? A[gr * 96 + c] : 0.0f;
    }
    __syncthreads();

    int r = tid >> 2;
    int j0 = (tid & 3) * 24;
    float acc[24];
#pragma unroll
    for (int jj = 0; jj < 24; ++jj) acc[jj] = 0.0f;

    for (int k = 0; k < 96; ++k) {
        float a = sA[r][k];
#pragma unroll
        for (int jj = 0; jj < 24; ++jj) acc[jj] += a * sW[k * 96 + j0 + jj];
    }

    int gr = row0 + r;
    if (gr < nrows) {
#pragma unroll
        for (int jj = 0; jj < 24; jj += 4) {
            float4 v = make_float4(acc[jj], acc[jj + 1], acc[jj + 2], acc[jj + 3]);
            *reinterpret_cast<float4*>(&C[gr * 96 + j0 + jj]) = v;
        }
    }
}

// ---------------- gather aggregation (self-loop fused) ----------------
// 32 threads per dst node; thread t owns cols {t, t+32, t+64}
__global__ __launch_bounds__(256) void k_gather(const float* __restrict__ hw,
                                                const float* __restrict__ dinv,
                                                const int* __restrict__ row_ptr,
                                                const int* __restrict__ col,
                                                const float* __restrict__ coef,
                                                float* __restrict__ agg) {
    int gid = blockIdx.x * blockDim.x + threadIdx.x;
    int n = gid >> 5;
    if (n >= NN) return;
    int t = gid & 31;
    float dn = dinv[n];
    float sc = dn * dn;
    const float* hn = &hw[(size_t)n * 96];
    float a0 = hn[t] * sc, a1 = hn[t + 32] * sc, a2 = hn[t + 64] * sc;
    int beg = row_ptr[n], end = row_ptr[n + 1];
    for (int p = beg; p < end; ++p) {
        int s = col[p];
        float c = coef[p];
        const float* hs = &hw[(size_t)s * 96];
        a0 += hs[t] * c;
        a1 += hs[t + 32] * c;
        a2 += hs[t + 64] * c;
    }
    float* an = &agg[(size_t)n * 96];
    an[t] = a0; an[t + 32] = a1; an[t + 64] = a2;
}

// ---------------- per-column sum / sumsq ----------------
__global__ void k_colstats(const float* __restrict__ h, float* __restrict__ stats) {
    __shared__ float ssum[96], ssq[96];
    int tid = threadIdx.x;
    if (tid < 96) { ssum[tid] = 0.0f; ssq[tid] = 0.0f; }
    __syncthreads();
    for (int i = blockIdx.x * blockDim.x + tid; i < NN * HH; i += gridDim.x * blockDim.x) {
        float v = h[i];
        int j = i % 96;
        atomicAdd(&ssum[j], v);
        atomicAdd(&ssq[j], v * v);
    }
    __syncthreads();
    if (tid < 96) {
        atomicAdd(&stats[tid], ssum[tid]);
        atomicAdd(&stats[96 + tid], ssq[tid]);
    }
}

// ---------------- fold mean/var into per-column scale/shift ----------------
__global__ void k_bnprep(float* __restrict__ stats, const float* __restrict__ g,
                         const float* __restrict__ be) {
    int j = threadIdx.x;
    if (j < 96) {
        float m = stats[j] * (1.0f / NN);
        float var = stats[96 + j] * (1.0f / NN) - m * m;
        float sc = g[j] * rsqrtf(var + EPSV);
        stats[j] = sc;
        stats[96 + j] = be[j] - m * sc;
    }
}

// ---------------- h_new = relu(agg*sc + sh) + h_prev ----------------
__global__ void k_bnapply(const float* __restrict__ agg, const float* __restrict__ hprev,
                          const float* __restrict__ stats, float* __restrict__ hnew) {
    int i = blockIdx.x * blockDim.x + threadIdx.x;
    if (i >= NN * HH) return;
    int j = i % 96;
    float v = fmaxf(agg[i] * stats[j] + stats[96 + j], 0.0f);
    hnew[i] = v + hprev[i];
}

// ---------------- segment-sum pooling ----------------
__global__ void k_pool(const float* __restrict__ h, const int* __restrict__ batch,
                       float* __restrict__ pooled, float* __restrict__ counts) {
    int i = blockIdx.x * blockDim.x + threadIdx.x;
    if (i >= NN * HH) return;
    int n = i / 96, j = i % 96;
    int b = batch[n];
    atomicAdd(&pooled[b * 96 + j], h[i]);
    if (j == 0) atomicAdd(&counts[b], 1.0f);
}

// ---------------- out = LN(pooled/cnt @ W_out + b_out) ----------------
__global__ __launch_bounds__(192) void k_out(const float* __restrict__ pooled,
                                             const float* __restrict__ counts,
                                             const float* __restrict__ Wout,
                                             const float* __restrict__ bout,
                                             const float* __restrict__ lg,
                                             const float* __restrict__ lb,
                                             float* __restrict__ out) {
    __shared__ float sp[96];
    __shared__ float smv[2];
    int b = blockIdx.x, t = threadIdx.x;
    float inv = 1.0f / fmaxf(counts[b], 1.0f);
    if (t < 96) sp[t] = pooled[b * 96 + t] * inv;
    __syncthreads();

    float acc = bout[t];
    for (int k = 0; k < 96; ++k) acc += sp[k] * Wout[k * 192 + t];

    __shared__ float svals[192];
    svals[t] = acc;
    __syncthreads();
    if (t < 64) {
        float a0 = svals[t], a1 = svals[t + 64], a2 = svals[t + 128];
        float s = a0 + a1 + a2;
        float s2 = a0 * a0 + a1 * a1 + a2 * a2;
        for (int o = 32; o > 0; o >>= 1) {
            s += __shfl_down(s, o, 64);
            s2 += __shfl_down(s2, o, 64);
        }
        if (t == 0) { smv[0] = s * (1.0f / 192.0f); smv[1] = s2 * (1.0f / 192.0f); }
    }
    __syncthreads();
    float m = smv[0];
    float var = smv[1] - m * m;
    float r = rsqrtf(var + EPSV);
    out[b * 192 + t] = lg[t] * (acc - m) * r + lb[t];
}

extern "C" void kernel_launch(void* const* d_in, const int* in_sizes, int n_in,
                              void* d_out, int out_size, void* d_ws, size_t ws_size,
                              hipStream_t stream) {
    const float* x    = (const float*)d_in[0];
    const int*   ei   = (const int*)  d_in[1];
    const int*   batch= (const int*)  d_in[2];
    const float* Win  = (const float*)d_in[3];
    const float* bin  = (const float*)d_in[4];
    const float* W1   = (const float*)d_in[5];
    const float* g1   = (const float*)d_in[7];
    const float* be1  = (const float*)d_in[8];
    const float* W2   = (const float*)d_in[9];
    const float* g2   = (const float*)d_in[11];
    const float* be2  = (const float*)d_in[12];
    const float* Wout = (const float*)d_in[13];
    const float* bout = (const float*)d_in[14];
    const float* lg   = (const float*)d_in[15];
    const float* lb   = (const float*)d_in[16];
    const int* src = ei;
    const int* dst = ei + EE;

    float* ws     = (float*)d_ws;
    float* hA     = ws;                        // [N,H]
    float* hB     = hA + (size_t)NN * HH;      // [N,H]
    float* hC     = hB + (size_t)NN * HH;      // [N,H]
    float* dinv   = hC + (size_t)NN * HH;      // [N]
    float* stats  = dinv + NN;                 // [2H]
    float* pooled = stats + 2 * HH;            // [B,H]
    float* counts = pooled + (size_t)BB * HH;  // [B]
    float* coef   = counts + BB;               // [E]
    int*   degi   = (int*)(coef + EE);         // [N]
    int*   row_ptr= degi + NN;                 // [N+1]
    int*   cursor = row_ptr + NN + 1;          // [N]
    int*   col    = cursor + NN;               // [E]

    const int NH = NN * HH;
    const int TB = 256;

    // ---- CSR build (dst-grouped; shared by both layers) ----
    hipMemsetAsync(degi, 0, NN * sizeof(int), stream);
    k_deghist<<<(EE + TB - 1) / TB, TB, 0, stream>>>(dst, degi);
    k_dinv<<<(NN + TB - 1) / TB, TB, 0, stream>>>(degi, dinv);
    k_scan<<<1, 1024, 0, stream>>>(degi, row_ptr);
    hipMemcpyAsync(cursor, row_ptr, NN * sizeof(int), hipMemcpyDeviceToDevice, stream);
    k_fill<<<(EE + TB - 1) / TB, TB, 0, stream>>>(src, dst, dinv, cursor, col, coef);

    // input layer -> hA
    k_inlayer<<<(NH + TB - 1) / TB, TB, 0, stream>>>(x, Win, bin, hA);

    const float* Ws[2]  = {W1, W2};
    const float* gs[2]  = {g1, g2};
    const float* bes[2] = {be1, be2};
    float* prev[2] = {hA, hB};
    float* hw[2]   = {hB, hC};
    float* agg[2]  = {hC, hA};
    float* hnew[2] = {hB, hC};

    for (int l = 0; l < 2; ++l) {
        k_gemm96<<<(NN + 63) / 64, TB, 0, stream>>>(prev[l], Ws[l], hw[l], NN);
        k_gather<<<(NN * 32 + TB - 1) / TB, TB, 0, stream>>>(hw[l], dinv, row_ptr, col, coef, agg[l]);
        hipMemsetAsync(stats, 0, 2 * HH * sizeof(float), stream);
        k_colstats<<<1024, TB, 0, stream>>>(agg[l], stats);
        k_bnprep<<<1, 128, 0, stream>>>(stats, gs[l], bes[l]);
        k_bnapply<<<(NH + TB - 1) / TB, TB, 0, stream>>>(agg[l], prev[l], stats, hnew[l]);
    }

    // pooling
    hipMemsetAsync(pooled, 0, (size_t)(BB * HH + BB) * sizeof(float), stream);
    k_pool<<<(NH + TB - 1) / TB, TB, 0, stream>>>(hC, batch, pooled, counts);

    // readout + layernorm
    k_out<<<BB, 192, 0, stream>>>(pooled, counts, Wout, bout, lg, lb, (float*)d_out);
}

// Round 3
// 462.401 us; speedup vs baseline: 5.1807x; 1.2374x over previous
//
#include <hip/hip_runtime.h>
#include <hip/hip_bf16.h>

#define NN 50000
#define EE 800000
#define BB 512
#define HH 96
#define DIN 5
#define DOUT 192
#define EPSV 1e-5f

// ---------------- degree histogram (int) ----------------
__global__ void k_deghist(const int* __restrict__ dst, int* __restrict__ degi) {
    int e = blockIdx.x * blockDim.x + threadIdx.x;
    if (e < EE) atomicAdd(&degi[dst[e]], 1);
}

__global__ void k_dinv(const int* __restrict__ degi, float* __restrict__ dinv) {
    int i = blockIdx.x * blockDim.x + threadIdx.x;
    if (i < NN) dinv[i] = rsqrtf((float)degi[i] + 1.0f);
}

// ---------------- exclusive prefix sum over degi -> row_ptr AND cursor ----------------
__global__ __launch_bounds__(1024) void k_scan(const int* __restrict__ degi,
                                               int* __restrict__ row_ptr,
                                               int* __restrict__ cursor) {
    __shared__ int wsum[16];
    __shared__ int woff[16];
    __shared__ int carry_s;
    int tid = threadIdx.x;
    int lane = tid & 63, w = tid >> 6;
    if (tid == 0) carry_s = 0;
    __syncthreads();
    for (int base = 0; base < NN; base += 1024) {
        int i = base + tid;
        int v = (i < NN) ? degi[i] : 0;
        int x = v;
#pragma unroll
        for (int o = 1; o < 64; o <<= 1) {
            int y = __shfl_up(x, o, 64);
            if (lane >= o) x += y;
        }
        if (lane == 63) wsum[w] = x;
        __syncthreads();
        if (tid == 0) {
            int c = carry_s;
#pragma unroll
            for (int k = 0; k < 16; ++k) { woff[k] = c; c += wsum[k]; }
            carry_s = c;
        }
        __syncthreads();
        if (i < NN) { int rp = woff[w] + x - v; row_ptr[i] = rp; cursor[i] = rp; }
        __syncthreads();
    }
    if (tid == 0) row_ptr[NN] = carry_s;
}

// ---------------- CSR fill: group edges by dst, precompute coef ----------------
__global__ void k_fill(const int* __restrict__ src, const int* __restrict__ dst,
                       const float* __restrict__ dinv, int* __restrict__ cursor,
                       int* __restrict__ col, float* __restrict__ coef) {
    int e = blockIdx.x * blockDim.x + threadIdx.x;
    if (e >= EE) return;
    int s = src[e], d = dst[e];
    int p = atomicAdd(&cursor[d], 1);
    col[p] = s;
    coef[p] = dinv[s] * dinv[d];
}

// ---------------- input layer: h = relu(x @ W_in + b_in) ----------------
__global__ void k_inlayer(const float* __restrict__ x, const float* __restrict__ Win,
                          const float* __restrict__ bin, float* __restrict__ h) {
    int i = blockIdx.x * blockDim.x + threadIdx.x;
    if (i >= NN * HH) return;
    int n = i / HH, j = i % HH;
    float acc = bin[j];
#pragma unroll
    for (int k = 0; k < DIN; ++k) acc += x[n * DIN + k] * Win[k * HH + j];
    h[i] = fmaxf(acc, 0.0f);
}

// ---------------- 96x96 GEMM: C[n,:] = A[n,:] @ W ----------------
__global__ __launch_bounds__(256) void k_gemm96(const float* __restrict__ A,
                                                const float* __restrict__ W,
                                                float* __restrict__ C, int nrows) {
    __shared__ float sA[64][100];
    __shared__ float sW[96 * 96];
    int tid = threadIdx.x;
    int row0 = blockIdx.x * 64;

    for (int i = tid; i < 96 * 96; i += 256) sW[i] = W[i];
    for (int i = tid; i < 64 * 96; i += 256) {
        int r = i / 96, c = i % 96;
        int gr = row0 + r;
        sA[r][c] = (gr < nrows) ? A[gr * 96 + c] : 0.0f;
    }
    __syncthreads();

    int r = tid >> 2;
    int j0 = (tid & 3) * 24;
    float acc[24];
#pragma unroll
    for (int jj = 0; jj < 24; ++jj) acc[jj] = 0.0f;

    for (int k = 0; k < 96; ++k) {
        float a = sA[r][k];
#pragma unroll
        for (int jj = 0; jj < 24; ++jj) acc[jj] += a * sW[k * 96 + j0 + jj];
    }

    int gr = row0 + r;
    if (gr < nrows) {
#pragma unroll
        for (int jj = 0; jj < 24; jj += 4) {
            float4 v = make_float4(acc[jj], acc[jj + 1], acc[jj + 2], acc[jj + 3]);
            *reinterpret_cast<float4*>(&C[gr * 96 + j0 + jj]) = v;
        }
    }
}

// ---------------- gather aggregation (self-loop fused) ----------------
__global__ __launch_bounds__(256) void k_gather(const float* __restrict__ hw,
                                                const float* __restrict__ dinv,
                                                const int* __restrict__ row_ptr,
                                                const int* __restrict__ col,
                                                const float* __restrict__ coef,
                                                float* __restrict__ agg) {
    int gid = blockIdx.x * blockDim.x + threadIdx.x;
    int n = gid >> 5;
    if (n >= NN) return;
    int t = gid & 31;
    float dn = dinv[n];
    float sc = dn * dn;
    const float* hn = &hw[(size_t)n * 96];
    float a0 = hn[t] * sc, a1 = hn[t + 32] * sc, a2 = hn[t + 64] * sc;
    int beg = row_ptr[n], end = row_ptr[n + 1];
    for (int p = beg; p < end; ++p) {
        int s = col[p];
        float c = coef[p];
        const float* hs = &hw[(size_t)s * 96];
        a0 += hs[t] * c;
        a1 += hs[t + 32] * c;
        a2 += hs[t + 64] * c;
    }
    float* an = &agg[(size_t)n * 96];
    an[t] = a0; an[t + 32] = a1; an[t + 64] = a2;
}

// ---------------- per-column sum / sumsq (privatized, no per-element atomics) ----------------
__global__ __launch_bounds__(192) void k_colstats(const float* __restrict__ h,
                                                  float* __restrict__ stats) {
    int col = threadIdx.x % 96, half = threadIdx.x / 96;
    int rows_per_block = (NN + gridDim.x - 1) / gridDim.x;
    int r0 = blockIdx.x * rows_per_block;
    int r1 = min(r0 + rows_per_block, NN);
    float s = 0.0f, s2 = 0.0f;
    for (int r = r0 + half; r < r1; r += 2) {
        float v = h[(size_t)r * 96 + col];
        s += v; s2 += v * v;
    }
    __shared__ float sh[2][2][96];
    sh[0][half][col] = s;
    sh[1][half][col] = s2;
    __syncthreads();
    if (threadIdx.x < 96) {
        atomicAdd(&stats[threadIdx.x], sh[0][0][threadIdx.x] + sh[0][1][threadIdx.x]);
        atomicAdd(&stats[96 + threadIdx.x], sh[1][0][threadIdx.x] + sh[1][1][threadIdx.x]);
    }
}

// ---------------- fold mean/var into per-column scale/shift ----------------
__global__ void k_bnprep(float* __restrict__ stats, const float* __restrict__ g,
                         const float* __restrict__ be) {
    int j = threadIdx.x;
    if (j < 96) {
        float m = stats[j] * (1.0f / NN);
        float var = stats[96 + j] * (1.0f / NN) - m * m;
        float sc = g[j] * rsqrtf(var + EPSV);
        stats[j] = sc;
        stats[96 + j] = be[j] - m * sc;
    }
}

// ---------------- h_new = relu(agg*sc + sh) + h_prev ----------------
__global__ void k_bnapply(const float* __restrict__ agg, const float* __restrict__ hprev,
                          const float* __restrict__ stats, float* __restrict__ hnew) {
    int i = blockIdx.x * blockDim.x + threadIdx.x;
    if (i >= NN * HH) return;
    int j = i % 96;
    float v = fmaxf(agg[i] * stats[j] + stats[96 + j], 0.0f);
    hnew[i] = v + hprev[i];
}

// ---------------- fused: segment-mean-pool + GEMM(96x192) + LayerNorm ----------------
__device__ inline int lower_bound_i(const int* __restrict__ a, int n, int v) {
    int lo = 0, hi = n;
    while (lo < hi) { int mid = (lo + hi) >> 1; if (a[mid] < v) lo = mid + 1; else hi = mid; }
    return lo;
}

__global__ __launch_bounds__(192) void k_out(const float* __restrict__ h,
                                             const int* __restrict__ batch,
                                             const float* __restrict__ Wout,
                                             const float* __restrict__ bout,
                                             const float* __restrict__ lg,
                                             const float* __restrict__ lb,
                                             float* __restrict__ out) {
    int b = blockIdx.x, t = threadIdx.x;
    int lo = lower_bound_i(batch, NN, b);
    int hi = lower_bound_i(batch, NN, b + 1);

    // segment sum: thread = (col t%96, row-half t/96)
    int col = t % 96, half = t / 96;
    float accp = 0.0f;
    for (int r = lo + half; r < hi; r += 2) accp += h[(size_t)r * 96 + col];

    __shared__ float sp2[2][96];
    __shared__ float sp[96];
    sp2[half][col] = accp;
    __syncthreads();
    if (t < 96) {
        float inv = (hi > lo) ? 1.0f / (float)(hi - lo) : 0.0f;
        sp[t] = (sp2[0][t] + sp2[1][t]) * inv;
    }
    __syncthreads();

    // GEMM: out col t
    float acc = bout[t];
    for (int k = 0; k < 96; ++k) acc += sp[k] * Wout[k * 192 + t];

    // LayerNorm over 192 cols
    __shared__ float svals[192];
    __shared__ float smv[2];
    svals[t] = acc;
    __syncthreads();
    if (t < 64) {
        float a0 = svals[t], a1 = svals[t + 64], a2 = svals[t + 128];
        float s = a0 + a1 + a2;
        float s2 = a0 * a0 + a1 * a1 + a2 * a2;
        for (int o = 32; o > 0; o >>= 1) {
            s += __shfl_down(s, o, 64);
            s2 += __shfl_down(s2, o, 64);
        }
        if (t == 0) { smv[0] = s * (1.0f / 192.0f); smv[1] = s2 * (1.0f / 192.0f); }
    }
    __syncthreads();
    float m = smv[0];
    float var = smv[1] - m * m;
    float r = rsqrtf(var + EPSV);
    out[b * 192 + t] = lg[t] * (acc - m) * r + lb[t];
}

extern "C" void kernel_launch(void* const* d_in, const int* in_sizes, int n_in,
                              void* d_out, int out_size, void* d_ws, size_t ws_size,
                              hipStream_t stream) {
    const float* x    = (const float*)d_in[0];
    const int*   ei   = (const int*)  d_in[1];
    const int*   batch= (const int*)  d_in[2];
    const float* Win  = (const float*)d_in[3];
    const float* bin  = (const float*)d_in[4];
    const float* W1   = (const float*)d_in[5];
    const float* g1   = (const float*)d_in[7];
    const float* be1  = (const float*)d_in[8];
    const float* W2   = (const float*)d_in[9];
    const float* g2   = (const float*)d_in[11];
    const float* be2  = (const float*)d_in[12];
    const float* Wout = (const float*)d_in[13];
    const float* bout = (const float*)d_in[14];
    const float* lg   = (const float*)d_in[15];
    const float* lb   = (const float*)d_in[16];
    const int* src = ei;
    const int* dst = ei + EE;

    float* ws     = (float*)d_ws;
    float* hA     = ws;                        // [N,H]
    float* hB     = hA + (size_t)NN * HH;      // [N,H]
    float* hC     = hB + (size_t)NN * HH;      // [N,H]
    float* dinv   = hC + (size_t)NN * HH;      // [N]
    float* stats  = dinv + NN;                 // [2H]
    float* coef   = stats + 2 * HH;            // [E]
    int*   degi   = (int*)(coef + EE);         // [N]
    int*   row_ptr= degi + NN;                 // [N+1]
    int*   cursor = row_ptr + NN + 1;          // [N]
    int*   col    = cursor + NN;               // [E]

    const int NH = NN * HH;
    const int TB = 256;

    // ---- CSR build (dst-grouped; shared by both layers) ----
    hipMemsetAsync(degi, 0, NN * sizeof(int), stream);
    k_deghist<<<(EE + TB - 1) / TB, TB, 0, stream>>>(dst, degi);
    k_dinv<<<(NN + TB - 1) / TB, TB, 0, stream>>>(degi, dinv);
    k_scan<<<1, 1024, 0, stream>>>(degi, row_ptr, cursor);
    k_fill<<<(EE + TB - 1) / TB, TB, 0, stream>>>(src, dst, dinv, cursor, col, coef);

    // input layer -> hA
    k_inlayer<<<(NH + TB - 1) / TB, TB, 0, stream>>>(x, Win, bin, hA);

    const float* Ws[2]  = {W1, W2};
    const float* gs[2]  = {g1, g2};
    const float* bes[2] = {be1, be2};
    float* prev[2] = {hA, hB};
    float* hw[2]   = {hB, hC};
    float* agg[2]  = {hC, hA};
    float* hnew[2] = {hB, hC};

    for (int l = 0; l < 2; ++l) {
        k_gemm96<<<(NN + 63) / 64, TB, 0, stream>>>(prev[l], Ws[l], hw[l], NN);
        k_gather<<<(NN * 32 + TB - 1) / TB, TB, 0, stream>>>(hw[l], dinv, row_ptr, col, coef, agg[l]);
        hipMemsetAsync(stats, 0, 2 * HH * sizeof(float), stream);
        k_colstats<<<256, 192, 0, stream>>>(agg[l], stats);
        k_bnprep<<<1, 128, 0, stream>>>(stats, gs[l], bes[l]);
        k_bnapply<<<(NH + TB - 1) / TB, TB, 0, stream>>>(agg[l], prev[l], stats, hnew[l]);
    }

    // fused pool + readout + layernorm
    k_out<<<BB, 192, 0, stream>>>(hC, batch, Wout, bout, lg, lb, (float*)d_out);
}

// Round 4
// 440.194 us; speedup vs baseline: 5.4421x; 1.0504x over previous
//
#include <hip/hip_runtime.h>
#include <hip/hip_bf16.h>

#define NN 50000
#define EE 800000
#define BB 512
#define HH 96
#define DIN 5
#define DOUT 192
#define EPSV 1e-5f

// ---------------- degree histogram (int) ----------------
__global__ void k_deghist(const int* __restrict__ dst, int* __restrict__ degi) {
    int e = blockIdx.x * blockDim.x + threadIdx.x;
    if (e < EE) atomicAdd(&degi[dst[e]], 1);
}

// ---------------- exclusive scan over degi -> row_ptr, cursor; also dinv ----------------
__global__ __launch_bounds__(1024) void k_scan(const int* __restrict__ degi,
                                               int* __restrict__ row_ptr,
                                               int* __restrict__ cursor,
                                               float* __restrict__ dinv) {
    __shared__ int wsum[16];
    __shared__ int woff[16];
    __shared__ int carry_s;
    int tid = threadIdx.x;
    int lane = tid & 63, w = tid >> 6;
    if (tid == 0) carry_s = 0;
    __syncthreads();
    for (int base = 0; base < NN; base += 1024) {
        int i = base + tid;
        int v = (i < NN) ? degi[i] : 0;
        if (i < NN) dinv[i] = rsqrtf((float)v + 1.0f);
        int x = v;
#pragma unroll
        for (int o = 1; o < 64; o <<= 1) {
            int y = __shfl_up(x, o, 64);
            if (lane >= o) x += y;
        }
        if (lane == 63) wsum[w] = x;
        __syncthreads();
        if (tid == 0) {
            int c = carry_s;
#pragma unroll
            for (int k = 0; k < 16; ++k) { woff[k] = c; c += wsum[k]; }
            carry_s = c;
        }
        __syncthreads();
        if (i < NN) { int rp = woff[w] + x - v; row_ptr[i] = rp; cursor[i] = rp; }
        __syncthreads();
    }
    if (tid == 0) row_ptr[NN] = carry_s;
}

// ---------------- CSR fill: col only (coef recomputed in gather) ----------------
__global__ void k_fill(const int* __restrict__ src, const int* __restrict__ dst,
                       int* __restrict__ cursor, int* __restrict__ col) {
    int e = blockIdx.x * blockDim.x + threadIdx.x;
    if (e >= EE) return;
    int s = src[e], d = dst[e];
    int p = atomicAdd(&cursor[d], 1);
    col[p] = s;
}

// ---------------- fused input layer + GEMM1: hA = relu(x@Win+bin); hw = hA@W1 ----------------
__global__ __launch_bounds__(256) void k_gemm_in(const float* __restrict__ x,
                                                 const float* __restrict__ Win,
                                                 const float* __restrict__ bin,
                                                 const float* __restrict__ W1,
                                                 float* __restrict__ hA,
                                                 float* __restrict__ hw) {
    __shared__ float sA[64][100];
    __shared__ float sW[96 * 96];
    __shared__ float sWin[5 * 96];
    __shared__ float sbin[96];
    int tid = threadIdx.x;
    int row0 = blockIdx.x * 64;

    for (int i = tid; i < 96 * 96; i += 256) sW[i] = W1[i];
    for (int i = tid; i < 5 * 96; i += 256) sWin[i] = Win[i];
    if (tid < 96) sbin[tid] = bin[tid];
    __syncthreads();

    int r = tid >> 2;
    int j0 = (tid & 3) * 24;
    int gr = row0 + r;

    // compute h row-tile: relu(x@Win+bin), stash in sA and write hA
    {
        float xv[5];
#pragma unroll
        for (int k = 0; k < DIN; ++k) xv[k] = (gr < NN) ? x[gr * DIN + k] : 0.0f;
        float hv[24];
#pragma unroll
        for (int jj = 0; jj < 24; ++jj) {
            float acc = sbin[j0 + jj];
#pragma unroll
            for (int k = 0; k < DIN; ++k) acc += xv[k] * sWin[k * 96 + j0 + jj];
            hv[jj] = fmaxf(acc, 0.0f);
            sA[r][j0 + jj] = hv[jj];
        }
        if (gr < NN) {
#pragma unroll
            for (int jj = 0; jj < 24; jj += 4) {
                float4 v = make_float4(hv[jj], hv[jj + 1], hv[jj + 2], hv[jj + 3]);
                *reinterpret_cast<float4*>(&hA[(size_t)gr * 96 + j0 + jj]) = v;
            }
        }
    }
    __syncthreads();

    float acc[24];
#pragma unroll
    for (int jj = 0; jj < 24; ++jj) acc[jj] = 0.0f;
    for (int k = 0; k < 96; ++k) {
        float a = sA[r][k];
#pragma unroll
        for (int jj = 0; jj < 24; ++jj) acc[jj] += a * sW[k * 96 + j0 + jj];
    }
    if (gr < NN) {
#pragma unroll
        for (int jj = 0; jj < 24; jj += 4) {
            float4 v = make_float4(acc[jj], acc[jj + 1], acc[jj + 2], acc[jj + 3]);
            *reinterpret_cast<float4*>(&hw[(size_t)gr * 96 + j0 + jj]) = v;
        }
    }
}

// ---------------- 96x96 GEMM: C[n,:] = A[n,:] @ W ----------------
__global__ __launch_bounds__(256) void k_gemm96(const float* __restrict__ A,
                                                const float* __restrict__ W,
                                                float* __restrict__ C, int nrows) {
    __shared__ float sA[64][100];
    __shared__ float sW[96 * 96];
    int tid = threadIdx.x;
    int row0 = blockIdx.x * 64;

    for (int i = tid; i < 96 * 96; i += 256) sW[i] = W[i];
    for (int i = tid; i < 64 * 96; i += 256) {
        int r = i / 96, c = i % 96;
        int gr = row0 + r;
        sA[r][c] = (gr < nrows) ? A[gr * 96 + c] : 0.0f;
    }
    __syncthreads();

    int r = tid >> 2;
    int j0 = (tid & 3) * 24;
    float acc[24];
#pragma unroll
    for (int jj = 0; jj < 24; ++jj) acc[jj] = 0.0f;

    for (int k = 0; k < 96; ++k) {
        float a = sA[r][k];
#pragma unroll
        for (int jj = 0; jj < 24; ++jj) acc[jj] += a * sW[k * 96 + j0 + jj];
    }

    int gr = row0 + r;
    if (gr < nrows) {
#pragma unroll
        for (int jj = 0; jj < 24; jj += 4) {
            float4 v = make_float4(acc[jj], acc[jj + 1], acc[jj + 2], acc[jj + 3]);
            *reinterpret_cast<float4*>(&C[gr * 96 + j0 + jj]) = v;
        }
    }
}

// ---------------- gather aggregation (self-loop fused, coef on-the-fly) ----------------
__global__ __launch_bounds__(256) void k_gather(const float* __restrict__ hw,
                                                const float* __restrict__ dinv,
                                                const int* __restrict__ row_ptr,
                                                const int* __restrict__ col,
                                                float* __restrict__ agg) {
    int gid = blockIdx.x * blockDim.x + threadIdx.x;
    int n = gid >> 5;
    if (n >= NN) return;
    int t = gid & 31;
    float dn = dinv[n];
    float sc = dn * dn;
    const float* hn = &hw[(size_t)n * 96];
    float a0 = hn[t] * sc, a1 = hn[t + 32] * sc, a2 = hn[t + 64] * sc;
    int beg = row_ptr[n], end = row_ptr[n + 1];
    for (int p = beg; p < end; ++p) {
        int s = col[p];
        float c = dinv[s] * dn;
        const float* hs = &hw[(size_t)s * 96];
        a0 += hs[t] * c;
        a1 += hs[t + 32] * c;
        a2 += hs[t + 64] * c;
    }
    float* an = &agg[(size_t)n * 96];
    an[t] = a0; an[t + 32] = a1; an[t + 64] = a2;
}

// ---------------- per-column sum / sumsq (privatized) ----------------
__global__ __launch_bounds__(192) void k_colstats(const float* __restrict__ h,
                                                  float* __restrict__ stats) {
    int col = threadIdx.x % 96, half = threadIdx.x / 96;
    int rows_per_block = (NN + gridDim.x - 1) / gridDim.x;
    int r0 = blockIdx.x * rows_per_block;
    int r1 = min(r0 + rows_per_block, NN);
    float s = 0.0f, s2 = 0.0f;
    for (int r = r0 + half; r < r1; r += 2) {
        float v = h[(size_t)r * 96 + col];
        s += v; s2 += v * v;
    }
    __shared__ float sh[2][2][96];
    sh[0][half][col] = s;
    sh[1][half][col] = s2;
    __syncthreads();
    if (threadIdx.x < 96) {
        atomicAdd(&stats[threadIdx.x], sh[0][0][threadIdx.x] + sh[0][1][threadIdx.x]);
        atomicAdd(&stats[96 + threadIdx.x], sh[1][0][threadIdx.x] + sh[1][1][threadIdx.x]);
    }
}

// ---------------- h_new = relu(agg*sc + sh) + h_prev   (bnprep folded in) ----------------
__global__ __launch_bounds__(256) void k_bnapply(const float4* __restrict__ agg,
                                                 const float4* __restrict__ hprev,
                                                 const float* __restrict__ stats,
                                                 const float* __restrict__ g,
                                                 const float* __restrict__ be,
                                                 float4* __restrict__ hnew) {
    __shared__ float ssc[96], ssh[96];
    int tid = threadIdx.x;
    if (tid < 96) {
        float m = stats[tid] * (1.0f / NN);
        float var = stats[96 + tid] * (1.0f / NN) - m * m;
        float sc = g[tid] * rsqrtf(var + EPSV);
        ssc[tid] = sc;
        ssh[tid] = be[tid] - m * sc;
    }
    __syncthreads();
    const int NH4 = NN * HH / 4;
    for (int i = blockIdx.x * blockDim.x + tid; i < NH4; i += gridDim.x * blockDim.x) {
        int j = (i % 24) * 4;
        float4 a = agg[i], p = hprev[i];
        float4 r;
        r.x = fmaxf(a.x * ssc[j]     + ssh[j],     0.0f) + p.x;
        r.y = fmaxf(a.y * ssc[j + 1] + ssh[j + 1], 0.0f) + p.y;
        r.z = fmaxf(a.z * ssc[j + 2] + ssh[j + 2], 0.0f) + p.z;
        r.w = fmaxf(a.w * ssc[j + 3] + ssh[j + 3], 0.0f) + p.w;
        hnew[i] = r;
    }
}

// ---------------- fused: segment-mean-pool + GEMM(96x192) + LayerNorm ----------------
__device__ inline int lower_bound_i(const int* __restrict__ a, int n, int v) {
    int lo = 0, hi = n;
    while (lo < hi) { int mid = (lo + hi) >> 1; if (a[mid] < v) lo = mid + 1; else hi = mid; }
    return lo;
}

__global__ __launch_bounds__(192) void k_out(const float* __restrict__ h,
                                             const int* __restrict__ batch,
                                             const float* __restrict__ Wout,
                                             const float* __restrict__ bout,
                                             const float* __restrict__ lg,
                                             const float* __restrict__ lb,
                                             float* __restrict__ out) {
    int b = blockIdx.x, t = threadIdx.x;
    int lo = lower_bound_i(batch, NN, b);
    int hi = lower_bound_i(batch, NN, b + 1);

    int col = t % 96, half = t / 96;
    float accp = 0.0f;
    for (int r = lo + half; r < hi; r += 2) accp += h[(size_t)r * 96 + col];

    __shared__ float sp2[2][96];
    __shared__ float sp[96];
    sp2[half][col] = accp;
    __syncthreads();
    if (t < 96) {
        float inv = (hi > lo) ? 1.0f / (float)(hi - lo) : 0.0f;
        sp[t] = (sp2[0][t] + sp2[1][t]) * inv;
    }
    __syncthreads();

    float acc = bout[t];
    for (int k = 0; k < 96; ++k) acc += sp[k] * Wout[k * 192 + t];

    __shared__ float svals[192];
    __shared__ float smv[2];
    svals[t] = acc;
    __syncthreads();
    if (t < 64) {
        float a0 = svals[t], a1 = svals[t + 64], a2 = svals[t + 128];
        float s = a0 + a1 + a2;
        float s2 = a0 * a0 + a1 * a1 + a2 * a2;
        for (int o = 32; o > 0; o >>= 1) {
            s += __shfl_down(s, o, 64);
            s2 += __shfl_down(s2, o, 64);
        }
        if (t == 0) { smv[0] = s * (1.0f / 192.0f); smv[1] = s2 * (1.0f / 192.0f); }
    }
    __syncthreads();
    float m = smv[0];
    float var = smv[1] - m * m;
    float r = rsqrtf(var + EPSV);
    out[b * 192 + t] = lg[t] * (acc - m) * r + lb[t];
}

extern "C" void kernel_launch(void* const* d_in, const int* in_sizes, int n_in,
                              void* d_out, int out_size, void* d_ws, size_t ws_size,
                              hipStream_t stream) {
    const float* x    = (const float*)d_in[0];
    const int*   ei   = (const int*)  d_in[1];
    const int*   batch= (const int*)  d_in[2];
    const float* Win  = (const float*)d_in[3];
    const float* bin  = (const float*)d_in[4];
    const float* W1   = (const float*)d_in[5];
    const float* g1   = (const float*)d_in[7];
    const float* be1  = (const float*)d_in[8];
    const float* W2   = (const float*)d_in[9];
    const float* g2   = (const float*)d_in[11];
    const float* be2  = (const float*)d_in[12];
    const float* Wout = (const float*)d_in[13];
    const float* bout = (const float*)d_in[14];
    const float* lg   = (const float*)d_in[15];
    const float* lb   = (const float*)d_in[16];
    const int* src = ei;
    const int* dst = ei + EE;

    float* ws     = (float*)d_ws;
    float* hA     = ws;                        // [N,H]
    float* hB     = hA + (size_t)NN * HH;      // [N,H]
    float* hC     = hB + (size_t)NN * HH;      // [N,H]
    float* dinv   = hC + (size_t)NN * HH;      // [N]
    float* stats  = dinv + NN;                 // [2H]
    int*   degi   = (int*)(stats + 2 * HH);    // [N]
    int*   row_ptr= degi + NN;                 // [N+1]
    int*   cursor = row_ptr + NN + 1;          // [N]
    int*   col    = cursor + NN;               // [E]

    const int TB = 256;

    // ---- CSR build (dst-grouped; shared by both layers) ----
    hipMemsetAsync(degi, 0, NN * sizeof(int), stream);
    k_deghist<<<(EE + TB - 1) / TB, TB, 0, stream>>>(dst, degi);
    k_scan<<<1, 1024, 0, stream>>>(degi, row_ptr, cursor, dinv);
    k_fill<<<(EE + TB - 1) / TB, TB, 0, stream>>>(src, dst, cursor, col);

    // ---- layer 0 (input layer fused into GEMM) ----
    k_gemm_in<<<(NN + 63) / 64, TB, 0, stream>>>(x, Win, bin, W1, hA, hB);
    k_gather<<<(NN * 32 + TB - 1) / TB, TB, 0, stream>>>(hB, dinv, row_ptr, col, hC);
    hipMemsetAsync(stats, 0, 2 * HH * sizeof(float), stream);
    k_colstats<<<256, 192, 0, stream>>>(hC, stats);
    k_bnapply<<<2048, TB, 0, stream>>>((const float4*)hC, (const float4*)hA, stats, g1, be1, (float4*)hB);

    // ---- layer 1 ----
    k_gemm96<<<(NN + 63) / 64, TB, 0, stream>>>(hB, W2, hC, NN);
    k_gather<<<(NN * 32 + TB - 1) / TB, TB, 0, stream>>>(hC, dinv, row_ptr, col, hA);
    hipMemsetAsync(stats, 0, 2 * HH * sizeof(float), stream);
    k_colstats<<<256, 192, 0, stream>>>(hA, stats);
    k_bnapply<<<2048, TB, 0, stream>>>((const float4*)hA, (const float4*)hB, stats, g2, be2, (float4*)hC);

    // ---- fused pool + readout + layernorm ----
    k_out<<<BB, 192, 0, stream>>>(hC, batch, Wout, bout, lg, lb, (float*)d_out);
}

// Round 5
// 375.087 us; speedup vs baseline: 6.3867x; 1.1736x over previous
//
#include <hip/hip_runtime.h>
#include <hip/hip_bf16.h>
#include <stdint.h>

#define NN 50000
#define EE 800000
#define BB 512
#define HH 96
#define DIN 5
#define DOUT 192
#define EPSV 1e-5f
#define NBANK 8
#define NB_GATHER 1024

__device__ inline float blo(uint32_t w) { return __uint_as_float(w << 16); }
__device__ inline float bhi(uint32_t w) { return __uint_as_float(w & 0xffff0000u); }
__device__ inline uint32_t packbf(float a, float b) {
    uint32_t ua = __float_as_uint(a); ua += 0x7fffu + ((ua >> 16) & 1u);
    uint32_t ub = __float_as_uint(b); ub += 0x7fffu + ((ub >> 16) & 1u);
    return (ua >> 16) | (ub & 0xffff0000u);
}

// ---------------- degree histogram (int) ----------------
__global__ void k_deghist(const int* __restrict__ dst, int* __restrict__ degi) {
    int e = blockIdx.x * blockDim.x + threadIdx.x;
    if (e < EE) atomicAdd(&degi[dst[e]], 1);
}

// ---------------- scan: row_ptr/cursor/dinv + zero stats ----------------
__global__ __launch_bounds__(1024) void k_scan(const int* __restrict__ degi,
                                               int* __restrict__ row_ptr,
                                               int* __restrict__ cursor,
                                               float* __restrict__ dinv,
                                               float* __restrict__ stats) {
    __shared__ int wsum[16];
    __shared__ int woff[16];
    __shared__ int carry_s;
    int tid = threadIdx.x;
    for (int i = tid; i < 2 * NBANK * 192; i += 1024) stats[i] = 0.0f;
    int lane = tid & 63, w = tid >> 6;
    if (tid == 0) carry_s = 0;
    __syncthreads();
    for (int base = 0; base < NN; base += 1024) {
        int i = base + tid;
        int v = (i < NN) ? degi[i] : 0;
        if (i < NN) dinv[i] = rsqrtf((float)v + 1.0f);
        int x = v;
#pragma unroll
        for (int o = 1; o < 64; o <<= 1) {
            int y = __shfl_up(x, o, 64);
            if (lane >= o) x += y;
        }
        if (lane == 63) wsum[w] = x;
        __syncthreads();
        if (tid == 0) {
            int c = carry_s;
#pragma unroll
            for (int k = 0; k < 16; ++k) { woff[k] = c; c += wsum[k]; }
            carry_s = c;
        }
        __syncthreads();
        if (i < NN) { int rp = woff[w] + x - v; row_ptr[i] = rp; cursor[i] = rp; }
        __syncthreads();
    }
    if (tid == 0) row_ptr[NN] = carry_s;
}

// ---------------- CSR fill: col only ----------------
__global__ void k_fill(const int* __restrict__ src, const int* __restrict__ dst,
                       int* __restrict__ cursor, int* __restrict__ col) {
    int e = blockIdx.x * blockDim.x + threadIdx.x;
    if (e >= EE) return;
    int s = src[e], d = dst[e];
    int p = atomicAdd(&cursor[d], 1);
    col[p] = s;
}

// ---------------- fused input layer + GEMM1 -> h0 (f32), hw1 (bf16) ----------------
__global__ __launch_bounds__(256) void k_gemm_in(const float* __restrict__ x,
                                                 const float* __restrict__ Win,
                                                 const float* __restrict__ bin,
                                                 const float* __restrict__ W1,
                                                 float* __restrict__ h0,
                                                 uint32_t* __restrict__ hwb) {
    __shared__ float sA[64][100];
    __shared__ float sW[96 * 96];
    __shared__ float sWin[5 * 96];
    __shared__ float sbin[96];
    int tid = threadIdx.x;
    int row0 = blockIdx.x * 64;

    for (int i = tid; i < 96 * 96; i += 256) sW[i] = W1[i];
    for (int i = tid; i < 5 * 96; i += 256) sWin[i] = Win[i];
    if (tid < 96) sbin[tid] = bin[tid];
    __syncthreads();

    int r = tid >> 2, q = tid & 3;
    int j0 = q * 24;
    int gr = row0 + r;

    {
        float xv[5];
#pragma unroll
        for (int k = 0; k < DIN; ++k) xv[k] = (gr < NN) ? x[gr * DIN + k] : 0.0f;
        float hv[24];
#pragma unroll
        for (int jj = 0; jj < 24; ++jj) {
            float acc = sbin[j0 + jj];
#pragma unroll
            for (int k = 0; k < DIN; ++k) acc += xv[k] * sWin[k * 96 + j0 + jj];
            hv[jj] = fmaxf(acc, 0.0f);
            sA[r][j0 + jj] = hv[jj];
        }
        if (gr < NN) {
#pragma unroll
            for (int jj = 0; jj < 24; jj += 4)
                *reinterpret_cast<float4*>(&h0[(size_t)gr * 96 + j0 + jj]) =
                    make_float4(hv[jj], hv[jj + 1], hv[jj + 2], hv[jj + 3]);
        }
    }
    __syncthreads();

    float acc[24];
#pragma unroll
    for (int jj = 0; jj < 24; ++jj) acc[jj] = 0.0f;
    for (int k = 0; k < 96; ++k) {
        float a = sA[r][k];
#pragma unroll
        for (int jj = 0; jj < 24; ++jj) acc[jj] += a * sW[k * 96 + j0 + jj];
    }
    if (gr < NN) {
        uint32_t wv[12];
#pragma unroll
        for (int p = 0; p < 12; ++p) wv[p] = packbf(acc[2 * p], acc[2 * p + 1]);
        uint4* dstp = reinterpret_cast<uint4*>(&hwb[(size_t)gr * 48 + q * 12]);
        dstp[0] = make_uint4(wv[0], wv[1], wv[2], wv[3]);
        dstp[1] = make_uint4(wv[4], wv[5], wv[6], wv[7]);
        dstp[2] = make_uint4(wv[8], wv[9], wv[10], wv[11]);
    }
}

// ---------------- gather (bf16 rows, self-loop + colstats fused) ----------------
// 16 threads per node; thread t owns word-slots {t, t+16, t+32} (cols 2t,2t+1, +32, +64)
__global__ __launch_bounds__(256) void k_gather(const uint32_t* __restrict__ hwb,
                                                const float* __restrict__ dinv,
                                                const int* __restrict__ row_ptr,
                                                const int* __restrict__ col,
                                                float* __restrict__ agg,
                                                float* __restrict__ stats) {
    int tid = threadIdx.x;
    int t = tid & 15, slot = tid >> 4;
    float cs[6] = {0, 0, 0, 0, 0, 0}, cq[6] = {0, 0, 0, 0, 0, 0};
    const int SLOTS = NB_GATHER * 16;
    for (int n = blockIdx.x * 16 + slot; n < NN; n += SLOTS) {
        float dn = dinv[n];
        float scf = dn * dn;
        const uint32_t* rn = hwb + (size_t)n * 48;
        uint32_t w0 = rn[t], w1 = rn[t + 16], w2 = rn[t + 32];
        float a0 = blo(w0) * scf, a1 = bhi(w0) * scf;
        float a2 = blo(w1) * scf, a3 = bhi(w1) * scf;
        float a4 = blo(w2) * scf, a5 = bhi(w2) * scf;
        int beg = row_ptr[n], end = row_ptr[n + 1];
        for (int p = beg; p < end; ++p) {
            int s = col[p];
            float c = dinv[s] * dn;
            const uint32_t* rs = hwb + (size_t)s * 48;
            uint32_t u0 = rs[t], u1 = rs[t + 16], u2 = rs[t + 32];
            a0 += blo(u0) * c; a1 += bhi(u0) * c;
            a2 += blo(u1) * c; a3 += bhi(u1) * c;
            a4 += blo(u2) * c; a5 += bhi(u2) * c;
        }
        float* an = agg + (size_t)n * 96;
        *reinterpret_cast<float2*>(&an[2 * t])      = make_float2(a0, a1);
        *reinterpret_cast<float2*>(&an[2 * t + 32]) = make_float2(a2, a3);
        *reinterpret_cast<float2*>(&an[2 * t + 64]) = make_float2(a4, a5);
        cs[0] += a0; cq[0] += a0 * a0; cs[1] += a1; cq[1] += a1 * a1;
        cs[2] += a2; cq[2] += a2 * a2; cs[3] += a3; cq[3] += a3 * a3;
        cs[4] += a4; cq[4] += a4 * a4; cs[5] += a5; cq[5] += a5 * a5;
    }
    __shared__ float red[2][96];
    if (tid < 96) { red[0][tid] = 0.0f; red[1][tid] = 0.0f; }
    __syncthreads();
    int c0 = 2 * t;
    int colsv[6] = {c0, c0 + 1, c0 + 32, c0 + 33, c0 + 64, c0 + 65};
#pragma unroll
    for (int k = 0; k < 6; ++k) {
        atomicAdd(&red[0][colsv[k]], cs[k]);
        atomicAdd(&red[1][colsv[k]], cq[k]);
    }
    __syncthreads();
    float* bank = stats + (blockIdx.x & (NBANK - 1)) * 192;
    if (tid < 96) {
        atomicAdd(&bank[tid], red[0][tid]);
        atomicAdd(&bank[96 + tid], red[1][tid]);
    }
}

// ---------------- fused BN+ReLU+residual + GEMM -> h1 (f32), hw2 (bf16) ----------------
__global__ __launch_bounds__(256) void k_gemm_bn(const float* __restrict__ agg,
                                                 const float* __restrict__ hprev,
                                                 const float* __restrict__ stats,
                                                 const float* __restrict__ g,
                                                 const float* __restrict__ be,
                                                 const float* __restrict__ W,
                                                 float* __restrict__ hnew,
                                                 uint32_t* __restrict__ hwb) {
    __shared__ float sA[64][100];
    __shared__ float sW[96 * 96];
    __shared__ float ssc[96], ssh[96];
    int tid = threadIdx.x;
    int row0 = blockIdx.x * 64;

    for (int i = tid; i < 96 * 96; i += 256) sW[i] = W[i];
    if (tid < 96) {
        float s = 0.0f, s2 = 0.0f;
#pragma unroll
        for (int k = 0; k < NBANK; ++k) { s += stats[k * 192 + tid]; s2 += stats[k * 192 + 96 + tid]; }
        float m = s * (1.0f / NN);
        float var = s2 * (1.0f / NN) - m * m;
        float sc = g[tid] * rsqrtf(var + EPSV);
        ssc[tid] = sc;
        ssh[tid] = be[tid] - m * sc;
    }
    __syncthreads();

    for (int i = tid; i < 64 * 24; i += 256) {
        int r = i / 24, qq = i % 24;
        int gr = row0 + r, c = qq * 4;
        float4 v = make_float4(0.0f, 0.0f, 0.0f, 0.0f);
        if (gr < NN) {
            float4 a = *reinterpret_cast<const float4*>(&agg[(size_t)gr * 96 + c]);
            float4 p = *reinterpret_cast<const float4*>(&hprev[(size_t)gr * 96 + c]);
            v.x = fmaxf(a.x * ssc[c]     + ssh[c],     0.0f) + p.x;
            v.y = fmaxf(a.y * ssc[c + 1] + ssh[c + 1], 0.0f) + p.y;
            v.z = fmaxf(a.z * ssc[c + 2] + ssh[c + 2], 0.0f) + p.z;
            v.w = fmaxf(a.w * ssc[c + 3] + ssh[c + 3], 0.0f) + p.w;
            *reinterpret_cast<float4*>(&hnew[(size_t)gr * 96 + c]) = v;
        }
        *reinterpret_cast<float4*>(&sA[r][c]) = v;
    }
    __syncthreads();

    int r = tid >> 2, q = tid & 3;
    int j0 = q * 24;
    int gr = row0 + r;
    float acc[24];
#pragma unroll
    for (int jj = 0; jj < 24; ++jj) acc[jj] = 0.0f;
    for (int k = 0; k < 96; ++k) {
        float a = sA[r][k];
#pragma unroll
        for (int jj = 0; jj < 24; ++jj) acc[jj] += a * sW[k * 96 + j0 + jj];
    }
    if (gr < NN) {
        uint32_t wv[12];
#pragma unroll
        for (int p = 0; p < 12; ++p) wv[p] = packbf(acc[2 * p], acc[2 * p + 1]);
        uint4* dstp = reinterpret_cast<uint4*>(&hwb[(size_t)gr * 48 + q * 12]);
        dstp[0] = make_uint4(wv[0], wv[1], wv[2], wv[3]);
        dstp[1] = make_uint4(wv[4], wv[5], wv[6], wv[7]);
        dstp[2] = make_uint4(wv[8], wv[9], wv[10], wv[11]);
    }
}

// ---------------- fused BN2 + pool + GEMM(96x192) + LayerNorm ----------------
__device__ inline int lower_bound_i(const int* __restrict__ a, int n, int v) {
    int lo = 0, hi = n;
    while (lo < hi) { int mid = (lo + hi) >> 1; if (a[mid] < v) lo = mid + 1; else hi = mid; }
    return lo;
}

__global__ __launch_bounds__(192) void k_out(const float* __restrict__ agg,
                                             const float* __restrict__ hprev,
                                             const float* __restrict__ stats,
                                             const float* __restrict__ g,
                                             const float* __restrict__ be,
                                             const int* __restrict__ batch,
                                             const float* __restrict__ Wout,
                                             const float* __restrict__ bout,
                                             const float* __restrict__ lg,
                                             const float* __restrict__ lb,
                                             float* __restrict__ out) {
    __shared__ float ssc[96], ssh[96];
    __shared__ float sp2[2][96];
    __shared__ float sp[96];
    int b = blockIdx.x, t = threadIdx.x;
    if (t < 96) {
        float s = 0.0f, s2 = 0.0f;
#pragma unroll
        for (int k = 0; k < NBANK; ++k) { s += stats[k * 192 + t]; s2 += stats[k * 192 + 96 + t]; }
        float m = s * (1.0f / NN);
        float var = s2 * (1.0f / NN) - m * m;
        float sc = g[t] * rsqrtf(var + EPSV);
        ssc[t] = sc;
        ssh[t] = be[t] - m * sc;
    }
    int lo = lower_bound_i(batch, NN, b);
    int hi = lower_bound_i(batch, NN, b + 1);
    __syncthreads();

    int colc = t % 96, half = t / 96;
    float scc = ssc[colc], shc = ssh[colc];
    float accp = 0.0f;
    for (int r = lo + half; r < hi; r += 2) {
        size_t idx = (size_t)r * 96 + colc;
        accp += fmaxf(agg[idx] * scc + shc, 0.0f) + hprev[idx];
    }
    sp2[half][colc] = accp;
    __syncthreads();
    if (t < 96) {
        float inv = (hi > lo) ? 1.0f / (float)(hi - lo) : 0.0f;
        sp[t] = (sp2[0][t] + sp2[1][t]) * inv;
    }
    __syncthreads();

    float acc = bout[t];
    for (int k = 0; k < 96; ++k) acc += sp[k] * Wout[k * 192 + t];

    __shared__ float svals[192];
    __shared__ float smv[2];
    svals[t] = acc;
    __syncthreads();
    if (t < 64) {
        float a0 = svals[t], a1 = svals[t + 64], a2 = svals[t + 128];
        float s = a0 + a1 + a2;
        float s2 = a0 * a0 + a1 * a1 + a2 * a2;
        for (int o = 32; o > 0; o >>= 1) {
            s += __shfl_down(s, o, 64);
            s2 += __shfl_down(s2, o, 64);
        }
        if (t == 0) { smv[0] = s * (1.0f / 192.0f); smv[1] = s2 * (1.0f / 192.0f); }
    }
    __syncthreads();
    float m = smv[0];
    float var = smv[1] - m * m;
    float rr = rsqrtf(var + EPSV);
    out[b * 192 + t] = lg[t] * (acc - m) * rr + lb[t];
}

extern "C" void kernel_launch(void* const* d_in, const int* in_sizes, int n_in,
                              void* d_out, int out_size, void* d_ws, size_t ws_size,
                              hipStream_t stream) {
    const float* x    = (const float*)d_in[0];
    const int*   ei   = (const int*)  d_in[1];
    const int*   batch= (const int*)  d_in[2];
    const float* Win  = (const float*)d_in[3];
    const float* bin  = (const float*)d_in[4];
    const float* W1   = (const float*)d_in[5];
    const float* g1   = (const float*)d_in[7];
    const float* be1  = (const float*)d_in[8];
    const float* W2   = (const float*)d_in[9];
    const float* g2   = (const float*)d_in[11];
    const float* be2  = (const float*)d_in[12];
    const float* Wout = (const float*)d_in[13];
    const float* bout = (const float*)d_in[14];
    const float* lg   = (const float*)d_in[15];
    const float* lb   = (const float*)d_in[16];
    const int* src = ei;
    const int* dst = ei + EE;

    float*    ws_f   = (float*)d_ws;
    float*    h0     = ws_f;                          // [N,96] f32
    float*    h1     = h0 + (size_t)NN * HH;          // [N,96] f32
    float*    agg    = h1 + (size_t)NN * HH;          // [N,96] f32 (reused both layers)
    float*    dinv   = agg + (size_t)NN * HH;         // [N]
    float*    stats  = dinv + NN;                     // [2 layers][NBANK][192]
    uint32_t* hwb    = (uint32_t*)(stats + 2 * NBANK * 192);  // [N,48] packed bf16 (reused)
    int*      degi   = (int*)(hwb + (size_t)NN * 48); // [N]
    int*      row_ptr= degi + NN;                     // [N+1]
    int*      cursor = row_ptr + NN + 1;              // [N]
    int*      col    = cursor + NN;                   // [E]

    const int TB = 256;
    float* stats1 = stats;
    float* stats2 = stats + NBANK * 192;

    // ---- CSR build (dst-grouped; shared by both layers) ----
    hipMemsetAsync(degi, 0, NN * sizeof(int), stream);
    k_deghist<<<(EE + TB - 1) / TB, TB, 0, stream>>>(dst, degi);
    k_scan<<<1, 1024, 0, stream>>>(degi, row_ptr, cursor, dinv, stats);
    k_fill<<<(EE + TB - 1) / TB, TB, 0, stream>>>(src, dst, cursor, col);

    // ---- layer 0: input MLP + GEMM1 fused ----
    k_gemm_in<<<(NN + 63) / 64, TB, 0, stream>>>(x, Win, bin, W1, h0, hwb);
    k_gather<<<NB_GATHER, TB, 0, stream>>>(hwb, dinv, row_ptr, col, agg, stats1);

    // ---- layer 1: BN1+res fused into GEMM2 ----
    k_gemm_bn<<<(NN + 63) / 64, TB, 0, stream>>>(agg, h0, stats1, g1, be1, W2, h1, hwb);
    k_gather<<<NB_GATHER, TB, 0, stream>>>(hwb, dinv, row_ptr, col, agg, stats2);

    // ---- BN2+res fused into pool + readout + layernorm ----
    k_out<<<BB, 192, 0, stream>>>(agg, h1, stats2, g2, be2, batch, Wout, bout, lg, lb,
                                  (float*)d_out);
}

// Round 6
// 330.165 us; speedup vs baseline: 7.2557x; 1.1361x over previous
//
#include <hip/hip_runtime.h>
#include <hip/hip_bf16.h>
#include <stdint.h>

#define NN 50000
#define EE 800000
#define BB 512
#define HH 96
#define DIN 5
#define DOUT 192
#define EPSV 1e-5f
#define NBANK 32
#define NB_GATHER 3125          // 3125 * 16 slots = 50000 nodes, 1 node/slot
#define NBLK_SCAN ((NN + 1023) / 1024)

__device__ inline float blo(uint32_t w) { return __uint_as_float(w << 16); }
__device__ inline float bhi(uint32_t w) { return __uint_as_float(w & 0xffff0000u); }
__device__ inline uint32_t packbf(float a, float b) {
    uint32_t ua = __float_as_uint(a); ua += 0x7fffu + ((ua >> 16) & 1u);
    uint32_t ub = __float_as_uint(b); ub += 0x7fffu + ((ub >> 16) & 1u);
    return (ua >> 16) | (ub & 0xffff0000u);
}

// ---------------- degree histogram (int) ----------------
__global__ void k_deghist(const int* __restrict__ dst, int* __restrict__ degi) {
    int e = blockIdx.x * blockDim.x + threadIdx.x;
    if (e < EE) atomicAdd(&degi[dst[e]], 1);
}

// ---------------- hierarchical scan, pass 1: in-block exclusive prescan ----------------
// writes per-element prescan into cursor (scratch), block totals into bsum; also dinv
__global__ __launch_bounds__(1024) void k_scan1(const int* __restrict__ degi,
                                                int* __restrict__ cursor,
                                                int* __restrict__ bsum,
                                                float* __restrict__ dinv) {
    __shared__ int wsum[16], woff[16];
    int i = blockIdx.x * 1024 + threadIdx.x;
    int v = (i < NN) ? degi[i] : 0;
    if (i < NN) dinv[i] = rsqrtf((float)v + 1.0f);
    int lane = threadIdx.x & 63, w = threadIdx.x >> 6;
    int x = v;
#pragma unroll
    for (int o = 1; o < 64; o <<= 1) {
        int y = __shfl_up(x, o, 64);
        if (lane >= o) x += y;
    }
    if (lane == 63) wsum[w] = x;
    __syncthreads();
    if (threadIdx.x == 0) {
        int c = 0;
#pragma unroll
        for (int k = 0; k < 16; ++k) { woff[k] = c; c += wsum[k]; }
        bsum[blockIdx.x] = c;
    }
    __syncthreads();
    if (i < NN) cursor[i] = woff[w] + x - v;
}

// ---------------- scan pass 2: scan 49 block totals; zero stats ----------------
__global__ __launch_bounds__(256) void k_scan2(int* __restrict__ bsum,
                                               int* __restrict__ row_ptr,
                                               float* __restrict__ stats) {
    int t = threadIdx.x;
    for (int i = t; i < 2 * NBANK * 192; i += 256) stats[i] = 0.0f;
    if (t == 0) {
        int c = 0;
        for (int k = 0; k < NBLK_SCAN; ++k) { int s = bsum[k]; bsum[k] = c; c += s; }
        row_ptr[NN] = c;
    }
}

// ---------------- scan pass 3: add block offsets -> row_ptr, cursor ----------------
__global__ __launch_bounds__(1024) void k_scan3(const int* __restrict__ bsum,
                                                int* __restrict__ row_ptr,
                                                int* __restrict__ cursor) {
    int i = blockIdx.x * 1024 + threadIdx.x;
    if (i < NN) {
        int rp = cursor[i] + bsum[blockIdx.x];
        row_ptr[i] = rp;
        cursor[i] = rp;
    }
}

// ---------------- CSR fill: col only ----------------
__global__ void k_fill(const int* __restrict__ src, const int* __restrict__ dst,
                       int* __restrict__ cursor, int* __restrict__ col) {
    int e = blockIdx.x * blockDim.x + threadIdx.x;
    if (e >= EE) return;
    int s = src[e], d = dst[e];
    int p = atomicAdd(&cursor[d], 1);
    col[p] = s;
}

// ---------------- fused input layer + GEMM1 -> h0 (f32), hw1 (bf16) ----------------
__global__ __launch_bounds__(256) void k_gemm_in(const float* __restrict__ x,
                                                 const float* __restrict__ Win,
                                                 const float* __restrict__ bin,
                                                 const float* __restrict__ W1,
                                                 float* __restrict__ h0,
                                                 uint32_t* __restrict__ hwb) {
    __shared__ float sA[64][100];
    __shared__ float sW[96 * 96];
    __shared__ float sWin[5 * 96];
    __shared__ float sbin[96];
    int tid = threadIdx.x;
    int row0 = blockIdx.x * 64;

    for (int i = tid; i < 96 * 96; i += 256) sW[i] = W1[i];
    for (int i = tid; i < 5 * 96; i += 256) sWin[i] = Win[i];
    if (tid < 96) sbin[tid] = bin[tid];
    __syncthreads();

    int r = tid >> 2, q = tid & 3;
    int j0 = q * 24;
    int gr = row0 + r;

    {
        float xv[5];
#pragma unroll
        for (int k = 0; k < DIN; ++k) xv[k] = (gr < NN) ? x[gr * DIN + k] : 0.0f;
        float hv[24];
#pragma unroll
        for (int jj = 0; jj < 24; ++jj) {
            float acc = sbin[j0 + jj];
#pragma unroll
            for (int k = 0; k < DIN; ++k) acc += xv[k] * sWin[k * 96 + j0 + jj];
            hv[jj] = fmaxf(acc, 0.0f);
            sA[r][j0 + jj] = hv[jj];
        }
        if (gr < NN) {
#pragma unroll
            for (int jj = 0; jj < 24; jj += 4)
                *reinterpret_cast<float4*>(&h0[(size_t)gr * 96 + j0 + jj]) =
                    make_float4(hv[jj], hv[jj + 1], hv[jj + 2], hv[jj + 3]);
        }
    }
    __syncthreads();

    float acc[24];
#pragma unroll
    for (int jj = 0; jj < 24; ++jj) acc[jj] = 0.0f;
    for (int k = 0; k < 96; ++k) {
        float a = sA[r][k];
#pragma unroll
        for (int jj = 0; jj < 24; ++jj) acc[jj] += a * sW[k * 96 + j0 + jj];
    }
    if (gr < NN) {
        uint32_t wv[12];
#pragma unroll
        for (int p = 0; p < 12; ++p) wv[p] = packbf(acc[2 * p], acc[2 * p + 1]);
        uint4* dstp = reinterpret_cast<uint4*>(&hwb[(size_t)gr * 48 + q * 12]);
        dstp[0] = make_uint4(wv[0], wv[1], wv[2], wv[3]);
        dstp[1] = make_uint4(wv[4], wv[5], wv[6], wv[7]);
        dstp[2] = make_uint4(wv[8], wv[9], wv[10], wv[11]);
    }
}

// ---------------- gather (bf16 rows, self-loop + colstats fused) ----------------
// 16 threads per node, exactly one node per slot; thread t owns word-slots {t, t+16, t+32}
__global__ __launch_bounds__(256) void k_gather(const uint32_t* __restrict__ hwb,
                                                const float* __restrict__ dinv,
                                                const int* __restrict__ row_ptr,
                                                const int* __restrict__ col,
                                                float* __restrict__ agg,
                                                float* __restrict__ stats) {
    int tid = threadIdx.x;
    int t = tid & 15, slot = tid >> 4;
    int n = blockIdx.x * 16 + slot;   // always < NN (3125*16 == 50000)

    float dn = dinv[n];
    float scf = dn * dn;
    const uint32_t* rn = hwb + (size_t)n * 48;
    uint32_t w0 = rn[t], w1 = rn[t + 16], w2 = rn[t + 32];
    float a0 = blo(w0) * scf, a1 = bhi(w0) * scf;
    float a2 = blo(w1) * scf, a3 = bhi(w1) * scf;
    float a4 = blo(w2) * scf, a5 = bhi(w2) * scf;
    int beg = row_ptr[n], end = row_ptr[n + 1];
#pragma unroll 4
    for (int p = beg; p < end; ++p) {
        int s = col[p];
        float c = dinv[s] * dn;
        const uint32_t* rs = hwb + (size_t)s * 48;
        uint32_t u0 = rs[t], u1 = rs[t + 16], u2 = rs[t + 32];
        a0 += blo(u0) * c; a1 += bhi(u0) * c;
        a2 += blo(u1) * c; a3 += bhi(u1) * c;
        a4 += blo(u2) * c; a5 += bhi(u2) * c;
    }
    float* an = agg + (size_t)n * 96;
    *reinterpret_cast<float2*>(&an[2 * t])      = make_float2(a0, a1);
    *reinterpret_cast<float2*>(&an[2 * t + 32]) = make_float2(a2, a3);
    *reinterpret_cast<float2*>(&an[2 * t + 64]) = make_float2(a4, a5);

    __shared__ float red[2][96];
    if (tid < 96) { red[0][tid] = 0.0f; red[1][tid] = 0.0f; }
    __syncthreads();
    int c0 = 2 * t;
    int colsv[6] = {c0, c0 + 1, c0 + 32, c0 + 33, c0 + 64, c0 + 65};
    float cs[6] = {a0, a1, a2, a3, a4, a5};
#pragma unroll
    for (int k = 0; k < 6; ++k) {
        atomicAdd(&red[0][colsv[k]], cs[k]);
        atomicAdd(&red[1][colsv[k]], cs[k] * cs[k]);
    }
    __syncthreads();
    float* bank = stats + (blockIdx.x & (NBANK - 1)) * 192;
    if (tid < 96) {
        atomicAdd(&bank[tid], red[0][tid]);
        atomicAdd(&bank[96 + tid], red[1][tid]);
    }
}

// ---------------- fused BN+ReLU+residual + GEMM -> h1 (f32), hw2 (bf16) ----------------
__global__ __launch_bounds__(256) void k_gemm_bn(const float* __restrict__ agg,
                                                 const float* __restrict__ hprev,
                                                 const float* __restrict__ stats,
                                                 const float* __restrict__ g,
                                                 const float* __restrict__ be,
                                                 const float* __restrict__ W,
                                                 float* __restrict__ hnew,
                                                 uint32_t* __restrict__ hwb) {
    __shared__ float sA[64][100];
    __shared__ float sW[96 * 96];
    __shared__ float ssc[96], ssh[96];
    int tid = threadIdx.x;
    int row0 = blockIdx.x * 64;

    for (int i = tid; i < 96 * 96; i += 256) sW[i] = W[i];
    if (tid < 96) {
        float s = 0.0f, s2 = 0.0f;
#pragma unroll
        for (int k = 0; k < NBANK; ++k) { s += stats[k * 192 + tid]; s2 += stats[k * 192 + 96 + tid]; }
        float m = s * (1.0f / NN);
        float var = s2 * (1.0f / NN) - m * m;
        float sc = g[tid] * rsqrtf(var + EPSV);
        ssc[tid] = sc;
        ssh[tid] = be[tid] - m * sc;
    }
    __syncthreads();

    for (int i = tid; i < 64 * 24; i += 256) {
        int r = i / 24, qq = i % 24;
        int gr = row0 + r, c = qq * 4;
        float4 v = make_float4(0.0f, 0.0f, 0.0f, 0.0f);
        if (gr < NN) {
            float4 a = *reinterpret_cast<const float4*>(&agg[(size_t)gr * 96 + c]);
            float4 p = *reinterpret_cast<const float4*>(&hprev[(size_t)gr * 96 + c]);
            v.x = fmaxf(a.x * ssc[c]     + ssh[c],     0.0f) + p.x;
            v.y = fmaxf(a.y * ssc[c + 1] + ssh[c + 1], 0.0f) + p.y;
            v.z = fmaxf(a.z * ssc[c + 2] + ssh[c + 2], 0.0f) + p.z;
            v.w = fmaxf(a.w * ssc[c + 3] + ssh[c + 3], 0.0f) + p.w;
            *reinterpret_cast<float4*>(&hnew[(size_t)gr * 96 + c]) = v;
        }
        *reinterpret_cast<float4*>(&sA[r][c]) = v;
    }
    __syncthreads();

    int r = tid >> 2, q = tid & 3;
    int j0 = q * 24;
    int gr = row0 + r;
    float acc[24];
#pragma unroll
    for (int jj = 0; jj < 24; ++jj) acc[jj] = 0.0f;
    for (int k = 0; k < 96; ++k) {
        float a = sA[r][k];
#pragma unroll
        for (int jj = 0; jj < 24; ++jj) acc[jj] += a * sW[k * 96 + j0 + jj];
    }
    if (gr < NN) {
        uint32_t wv[12];
#pragma unroll
        for (int p = 0; p < 12; ++p) wv[p] = packbf(acc[2 * p], acc[2 * p + 1]);
        uint4* dstp = reinterpret_cast<uint4*>(&hwb[(size_t)gr * 48 + q * 12]);
        dstp[0] = make_uint4(wv[0], wv[1], wv[2], wv[3]);
        dstp[1] = make_uint4(wv[4], wv[5], wv[6], wv[7]);
        dstp[2] = make_uint4(wv[8], wv[9], wv[10], wv[11]);
    }
}

// ---------------- fused BN2 + pool + GEMM(96x192) + LayerNorm ----------------
__device__ inline int lower_bound_i(const int* __restrict__ a, int n, int v) {
    int lo = 0, hi = n;
    while (lo < hi) { int mid = (lo + hi) >> 1; if (a[mid] < v) lo = mid + 1; else hi = mid; }
    return lo;
}

__global__ __launch_bounds__(192) void k_out(const float* __restrict__ agg,
                                             const float* __restrict__ hprev,
                                             const float* __restrict__ stats,
                                             const float* __restrict__ g,
                                             const float* __restrict__ be,
                                             const int* __restrict__ batch,
                                             const float* __restrict__ Wout,
                                             const float* __restrict__ bout,
                                             const float* __restrict__ lg,
                                             const float* __restrict__ lb,
                                             float* __restrict__ out) {
    __shared__ float ssc[96], ssh[96];
    __shared__ float sp2[2][96];
    __shared__ float sp[96];
    int b = blockIdx.x, t = threadIdx.x;
    if (t < 96) {
        float s = 0.0f, s2 = 0.0f;
#pragma unroll
        for (int k = 0; k < NBANK; ++k) { s += stats[k * 192 + t]; s2 += stats[k * 192 + 96 + t]; }
        float m = s * (1.0f / NN);
        float var = s2 * (1.0f / NN) - m * m;
        float sc = g[t] * rsqrtf(var + EPSV);
        ssc[t] = sc;
        ssh[t] = be[t] - m * sc;
    }
    int lo = lower_bound_i(batch, NN, b);
    int hi = lower_bound_i(batch, NN, b + 1);
    __syncthreads();

    int colc = t % 96, half = t / 96;
    float scc = ssc[colc], shc = ssh[colc];
    float accp = 0.0f;
    for (int r = lo + half; r < hi; r += 2) {
        size_t idx = (size_t)r * 96 + colc;
        accp += fmaxf(agg[idx] * scc + shc, 0.0f) + hprev[idx];
    }
    sp2[half][colc] = accp;
    __syncthreads();
    if (t < 96) {
        float inv = (hi > lo) ? 1.0f / (float)(hi - lo) : 0.0f;
        sp[t] = (sp2[0][t] + sp2[1][t]) * inv;
    }
    __syncthreads();

    float acc = bout[t];
    for (int k = 0; k < 96; ++k) acc += sp[k] * Wout[k * 192 + t];

    __shared__ float svals[192];
    __shared__ float smv[2];
    svals[t] = acc;
    __syncthreads();
    if (t < 64) {
        float a0 = svals[t], a1 = svals[t + 64], a2 = svals[t + 128];
        float s = a0 + a1 + a2;
        float s2 = a0 * a0 + a1 * a1 + a2 * a2;
        for (int o = 32; o > 0; o >>= 1) {
            s += __shfl_down(s, o, 64);
            s2 += __shfl_down(s2, o, 64);
        }
        if (t == 0) { smv[0] = s * (1.0f / 192.0f); smv[1] = s2 * (1.0f / 192.0f); }
    }
    __syncthreads();
    float m = smv[0];
    float var = smv[1] - m * m;
    float rr = rsqrtf(var + EPSV);
    out[b * 192 + t] = lg[t] * (acc - m) * rr + lb[t];
}

extern "C" void kernel_launch(void* const* d_in, const int* in_sizes, int n_in,
                              void* d_out, int out_size, void* d_ws, size_t ws_size,
                              hipStream_t stream) {
    const float* x    = (const float*)d_in[0];
    const int*   ei   = (const int*)  d_in[1];
    const int*   batch= (const int*)  d_in[2];
    const float* Win  = (const float*)d_in[3];
    const float* bin  = (const float*)d_in[4];
    const float* W1   = (const float*)d_in[5];
    const float* g1   = (const float*)d_in[7];
    const float* be1  = (const float*)d_in[8];
    const float* W2   = (const float*)d_in[9];
    const float* g2   = (const float*)d_in[11];
    const float* be2  = (const float*)d_in[12];
    const float* Wout = (const float*)d_in[13];
    const float* bout = (const float*)d_in[14];
    const float* lg   = (const float*)d_in[15];
    const float* lb   = (const float*)d_in[16];
    const int* src = ei;
    const int* dst = ei + EE;

    float*    ws_f   = (float*)d_ws;
    float*    h0     = ws_f;                          // [N,96] f32
    float*    h1     = h0 + (size_t)NN * HH;          // [N,96] f32
    float*    agg    = h1 + (size_t)NN * HH;          // [N,96] f32 (reused both layers)
    float*    dinv   = agg + (size_t)NN * HH;         // [N]
    float*    stats  = dinv + NN;                     // [2 layers][NBANK][192]
    uint32_t* hwb    = (uint32_t*)(stats + 2 * NBANK * 192);  // [N,48] packed bf16 (reused)
    int*      degi   = (int*)(hwb + (size_t)NN * 48); // [N]
    int*      row_ptr= degi + NN;                     // [N+1]
    int*      cursor = row_ptr + NN + 1;              // [N]
    int*      col    = cursor + NN;                   // [E]
    int*      bsum   = col + EE;                      // [NBLK_SCAN]

    const int TB = 256;
    float* stats1 = stats;
    float* stats2 = stats + NBANK * 192;

    // ---- CSR build (dst-grouped; shared by both layers) ----
    hipMemsetAsync(degi, 0, NN * sizeof(int), stream);
    k_deghist<<<(EE + TB - 1) / TB, TB, 0, stream>>>(dst, degi);
    k_scan1<<<NBLK_SCAN, 1024, 0, stream>>>(degi, cursor, bsum, dinv);
    k_scan2<<<1, 256, 0, stream>>>(bsum, row_ptr, stats);
    k_scan3<<<NBLK_SCAN, 1024, 0, stream>>>(bsum, row_ptr, cursor);
    k_fill<<<(EE + TB - 1) / TB, TB, 0, stream>>>(src, dst, cursor, col);

    // ---- layer 0: input MLP + GEMM1 fused ----
    k_gemm_in<<<(NN + 63) / 64, TB, 0, stream>>>(x, Win, bin, W1, h0, hwb);
    k_gather<<<NB_GATHER, TB, 0, stream>>>(hwb, dinv, row_ptr, col, agg, stats1);

    // ---- layer 1: BN1+res fused into GEMM2 ----
    k_gemm_bn<<<(NN + 63) / 64, TB, 0, stream>>>(agg, h0, stats1, g1, be1, W2, h1, hwb);
    k_gather<<<NB_GATHER, TB, 0, stream>>>(hwb, dinv, row_ptr, col, agg, stats2);

    // ---- BN2+res fused into pool + readout + layernorm ----
    k_out<<<BB, 192, 0, stream>>>(agg, h1, stats2, g2, be2, batch, Wout, bout, lg, lb,
                                  (float*)d_out);
}